// Round 18
// baseline (200.479 us; speedup 1.0000x reference)
//
#include <hip/hip_runtime.h>

#define TT 4096
#define T1 4097

using f32x4 = __attribute__((ext_vector_type(4))) float;

typedef const float __attribute__((address_space(1)))* gbl_fp;
typedef float __attribute__((address_space(3)))* lds_fp;
__device__ __forceinline__ void gload_lds16(const float* g, float* l) {
  __builtin_amdgcn_global_load_lds((gbl_fp)g, (lds_fp)l, 16, 0, 0);
}

// ---------------- shared GEMV body: Y[b][j] += sum_k X[b][k] * W[k][j] ------------
__device__ __forceinline__ void gemv_body(const float* __restrict__ X,
                                          const float* __restrict__ W,
                                          float* __restrict__ Y,
                                          int N, int K, int chunk, int ky) {
  const int tid = threadIdx.x;
  const int ct = tid & 7;
  const int kt = tid >> 3;
  const int col0 = blockIdx.x * 32 + ct * 4;
  const int k0 = ky * chunk;
  float acc[4][4];
#pragma unroll
  for (int c = 0; c < 4; ++c)
#pragma unroll
    for (int b = 0; b < 4; ++b) acc[c][b] = 0.f;
  const int iters = chunk >> 5;
  for (int i = 0; i < iters; ++i) {
    int k = k0 + kt + (i << 5);
    f32x4 w4 = *(const f32x4*)(W + (size_t)k * N + col0);
    float xb[4];
#pragma unroll
    for (int b = 0; b < 4; ++b) xb[b] = X[(size_t)b * K + k];
#pragma unroll
    for (int c = 0; c < 4; ++c)
#pragma unroll
      for (int b = 0; b < 4; ++b) acc[c][b] += w4[c] * xb[b];
  }
  __shared__ float red[256][16];
#pragma unroll
  for (int c = 0; c < 4; ++c)
#pragma unroll
    for (int b = 0; b < 4; ++b) red[tid][c * 4 + b] = acc[c][b];
  __syncthreads();
  for (int s = 16; s >= 1; s >>= 1) {
    if (kt < s) {
#pragma unroll
      for (int j = 0; j < 16; ++j) red[tid][j] += red[tid + 8 * s][j];
    }
    __syncthreads();
  }
  if (kt == 0) {
#pragma unroll
    for (int c = 0; c < 4; ++c)
#pragma unroll
      for (int b = 0; b < 4; ++b)
        atomicAdd(&Y[(size_t)b * N + col0 + c], red[ct][c * 4 + b]);
  }
}

// ---------------- hidden projections: W_DQ / W_DKV / W_KR in one launch -----------
__global__ __launch_bounds__(256) void gemv_hidden(const float* __restrict__ X,
                                                   const float* __restrict__ W0,
                                                   const float* __restrict__ W1,
                                                   const float* __restrict__ W2,
                                                   float* __restrict__ Ybase) {
  const int z = blockIdx.z;
  const float* W = (z == 0) ? W0 : (z == 1) ? W1 : W2;
  const int N = (z == 0) ? 1536 : (z == 1) ? 512 : 2048;
  const int nb = (z == 0) ? 48 : (z == 1) ? 16 : 64;
  const size_t yoff = (z == 0) ? 0 : (z == 1) ? 6144 : 8192;
  if ((int)blockIdx.x >= nb) return;
  gemv_body(X, W, Ybase + yoff, N, 4096, 512, blockIdx.y);
}

// ---------------- cQ projections: W_UQ_C / W_UQ_R in one launch -------------------
__global__ __launch_bounds__(256) void gemv_cq(const float* __restrict__ X,
                                               const float* __restrict__ W0,
                                               const float* __restrict__ W1,
                                               float* __restrict__ Y0,
                                               float* __restrict__ Y1) {
  const int z = blockIdx.z;
  const float* W = (z == 0) ? W0 : W1;
  float* Y = (z == 0) ? Y0 : Y1;
  const int N = (z == 0) ? 4096 : 2048;
  const int nb = (z == 0) ? 128 : 64;
  if ((int)blockIdx.x >= nb) return;
  gemv_body(X, W, Y, N, 1536, 384, blockIdx.y);
}

// ---------------- gemv for W_O ----------------------------------------------------
__global__ __launch_bounds__(256) void gemv_atomic(const float* __restrict__ X,
                                                   const float* __restrict__ W,
                                                   float* __restrict__ Y,
                                                   int N, int K, int chunk) {
  gemv_body(X, W, Y, N, K, chunk, blockIdx.y);
}

// ---------------- absorb: q_abs[b][n][v] + qT[b][v][n] ----------------------------
// grid (32 n, 4 vt); block 128: one thread per v
__global__ __launch_bounds__(128) void absorb_kernel(const float* __restrict__ qC,
                                                     const float* __restrict__ W_UK,
                                                     float* __restrict__ q_abs,
                                                     float* __restrict__ qT) {
  const int n = blockIdx.x, vt = blockIdx.y;
  __shared__ float qs[4][128];
  for (int i = threadIdx.x; i < 512; i += 128)
    qs[i >> 7][i & 127] = qC[(size_t)(i >> 7) * 4096 + n * 128 + (i & 127)];
  __syncthreads();
  const int v = vt * 128 + threadIdx.x;
  const float* wp = W_UK + (size_t)v * 4096 + n * 128;
  float acc[4] = {0.f, 0.f, 0.f, 0.f};
#pragma unroll 8
  for (int c = 0; c < 32; ++c) {
    f32x4 w4 = *(const f32x4*)(wp + c * 4);
#pragma unroll
    for (int j = 0; j < 4; ++j)
#pragma unroll
      for (int b = 0; b < 4; ++b) acc[b] += qs[b][c * 4 + j] * w4[j];
  }
#pragma unroll
  for (int b = 0; b < 4; ++b) {
    q_abs[((size_t)(b * 32) + n) * 512 + v] = acc[b];
    qT[((size_t)b * 512 + v) * 32 + n] = acc[b];
  }
}

// ---------------- scores + cache copies, block-specialized ------------------------
// grid 6144: bid%3<2 -> kR block (4096: 4 rows, 1 row/wave, global_load_lds)
//            bid%3==2 -> cKV block (2048: 8 rows, LDS tile + QK dot, nt copy)
// kR: 8x global_load_lds per wave (async queue, no VGPR dest -> compiler can't
// sink; 8KB/wave in flight), __syncthreads drains vmcnt, then ds_read + nt store
// + rope dot. Head n = k*4 + (l>>4), reduce over l&15 via shfl_xor.
__global__ __launch_bounds__(256, 4) void scores_split(const float* __restrict__ cKV,
                                                       const float* __restrict__ kR,
                                                       const float* __restrict__ qT,
                                                       const float* __restrict__ qR,
                                                       float* __restrict__ scores,
                                                       float* __restrict__ scoresR,
                                                       float* __restrict__ out_ckv,
                                                       float* __restrict__ out_kr) {
  const int bid = blockIdx.x;
  const int tid = threadIdx.x;
  __shared__ float sh[8192];  // 32 KB: kr uses 4x2048; ckv uses 8x516
  if (bid % 3 == 2) {
    // ---- cKV block: stage 8x512 tile, nt write-through copy, QK dot from LDS ----
    const int cidx = bid / 3;
    const int b = cidx >> 9;
    const int t0 = (cidx & 511) * 8;
    for (int i = tid; i < 1024; i += 256) {
      int tl = i >> 7, vq = i & 127;
      f32x4 v = *(const f32x4*)(cKV + ((size_t)b * TT + t0 + tl) * 512 + vq * 4);
      *(f32x4*)&sh[tl * 516 + vq * 4] = v;
      __builtin_nontemporal_store(v, (f32x4*)(out_ckv + ((size_t)b * T1 + t0 + tl) * 512 + vq * 4));
    }
    __syncthreads();
    const int tl = tid >> 5, n = tid & 31;
    const float* qtb = qT + (size_t)b * 16384 + n;
    float a = 0.f;
#pragma unroll 8
    for (int v = 0; v < 512; ++v) a += qtb[(size_t)v * 32] * sh[tl * 516 + v];
    scores[((size_t)(b * 32) + n) * T1 + t0 + tl] = a;
  } else {
    // ---- kR block: 1 row/wave via global_load_lds, then nt copy + rope scores ---
    const int kridx = (bid / 3) * 2 + (bid % 3);  // [0, 4096)
    const int w = tid >> 6, l = tid & 63;
    const int g = kridx * 4 + w;                  // global row [0, 16384)
    const int b = g >> 12, t = g & 4095;
    f32x4 q[8];
#pragma unroll
    for (int k = 0; k < 8; ++k)
      q[k] = *(const f32x4*)(qR + (size_t)b * 2048 + l * 4 + k * 256);
    const float* src = kR + ((size_t)b * TT + t) * 2048 + l * 4;
    float* lbase = &sh[w * 2048];
#pragma unroll
    for (int k = 0; k < 8; ++k) gload_lds16(src + k * 256, lbase + k * 256);
    __syncthreads();
    float* dst = out_kr + ((size_t)b * T1 + t) * 2048 + l * 4;
    f32x4 v[8];
#pragma unroll
    for (int k = 0; k < 8; ++k) v[k] = *(const f32x4*)(lbase + k * 256 + l * 4);
#pragma unroll
    for (int k = 0; k < 8; ++k)
      __builtin_nontemporal_store(v[k], (f32x4*)(dst + k * 256));
    float p[8];
#pragma unroll
    for (int k = 0; k < 8; ++k)
      p[k] = (q[k][0] * v[k][0] + q[k][1] * v[k][1]) +
             (q[k][2] * v[k][2] + q[k][3] * v[k][3]);
#pragma unroll
    for (int k = 0; k < 8; ++k) {
      p[k] += __shfl_xor(p[k], 1);
      p[k] += __shfl_xor(p[k], 2);
      p[k] += __shfl_xor(p[k], 4);
      p[k] += __shfl_xor(p[k], 8);
    }
    if ((l & 15) == 0) {
      const int nbase = l >> 4;
#pragma unroll
      for (int k = 0; k < 8; ++k)
        scoresR[((size_t)(b * 32) + k * 4 + nbase) * T1 + t] = p[k];
    }
  }
}

// ---------------- softmax stats: one online pass -> {M, 1/S, pTT/S} per row -------
// grid 128 (b*32+n); block 256
__global__ __launch_bounds__(256) void softmax_stats(const float* __restrict__ scores,
                                                     const float* __restrict__ scoresR,
                                                     const float* __restrict__ mask,
                                                     const float* __restrict__ q_abs,
                                                     const float* __restrict__ cKV_t,
                                                     const float* __restrict__ qR,
                                                     const float* __restrict__ kR_t,
                                                     float* __restrict__ stats) {
  const int b = blockIdx.x >> 5, n = blockIdx.x & 31;
  const int tid = threadIdx.x;
  const size_t row = (size_t)(b * 32) + n;
  const float* srow = scores + row * T1;
  const float* scrow = scoresR + row * T1;
  const float* mrow = mask + row * T1;
  const float* qa = q_abs + row * 512;
  const float* ck = cKV_t + b * 512;
  float p = qa[tid] * ck[tid] + qa[tid + 256] * ck[tid + 256];
  if (tid < 64) p += qR[(size_t)b * 2048 + n * 64 + tid] * kR_t[(size_t)b * 2048 + n * 64 + tid];
  __shared__ float lds[256];
  lds[tid] = p;
  __syncthreads();
  for (int s = 128; s >= 1; s >>= 1) {
    if (tid < s) lds[tid] += lds[tid + s];
    __syncthreads();
  }
  const float sT = lds[0];
  __syncthreads();
  const float isc = 0.0721687836487032f;  // 1/sqrt(192)
  float m = -1e30f, s = 0.f;
  for (int t = tid; t < TT; t += 256) {
    float val = (srow[t] + scrow[t]) * isc + mrow[t] * (-1e9f);
    if (val > m) {
      s = s * expf(m - val) + 1.f;
      m = val;
    } else {
      s += expf(val - m);
    }
  }
  __shared__ float lm[256], lsm[256];
  lm[tid] = m;
  lsm[tid] = s;
  __syncthreads();
  for (int st = 128; st >= 1; st >>= 1) {
    if (tid < st) {
      float m2 = lm[tid + st], s2 = lsm[tid + st];
      float M = fmaxf(lm[tid], m2);
      lsm[tid] = lsm[tid] * expf(lm[tid] - M) + s2 * expf(m2 - M);
      lm[tid] = M;
    }
    __syncthreads();
  }
  if (tid == 0) {
    float valT = sT * isc + mrow[TT] * (-1e9f);
    float M = fmaxf(lm[0], valT);
    float S = lsm[0] * expf(lm[0] - M) + expf(valT - M);
    stats[blockIdx.x * 4 + 0] = M;
    stats[blockIdx.x * 4 + 1] = 1.f / S;
    stats[blockIdx.x * 4 + 2] = expf(valT - M) / S;
  }
}

// ---------------- aggregation partials (probs computed on the fly) ----------------
// grid (NC, 4 b, 4 vh of 128 v); block 256: vg = tid&31 (4 v), ng = tid>>5 (4 n)
__global__ __launch_bounds__(256) void agg_part(const float* __restrict__ cKV,
                                                const float* __restrict__ scores,
                                                const float* __restrict__ scoresR,
                                                const float* __restrict__ mask,
                                                const float* __restrict__ stats,
                                                float* __restrict__ aggP,
                                                int tlen, int NC) {
  const int chunk = blockIdx.x, b = blockIdx.y, vh = blockIdx.z;
  const int tid = threadIdx.x;
  const int vg = tid & 31, ng = tid >> 5;
  const float isc = 0.0721687836487032f;
  __shared__ float p_lds[32 * 129];
  float acc[4][4];
#pragma unroll
  for (int a = 0; a < 4; ++a)
#pragma unroll
    for (int j = 0; j < 4; ++j) acc[a][j] = 0.f;
  const int sub = (tlen < 128) ? tlen : 128;
  const int sshift = (sub == 64) ? 6 : 7;
  for (int tt = 0; tt < tlen; tt += sub) {
    const int t0 = chunk * tlen + tt;
    __syncthreads();
    for (int i = tid; i < (sub << 5); i += 256) {
      int nn = i >> sshift, tl = i & (sub - 1);
      size_t row = (size_t)(b * 32) + nn;
      size_t off = row * T1 + t0 + tl;
      float val = (scores[off] + scoresR[off]) * isc + mask[off] * (-1e9f);
      p_lds[nn * 129 + tl] = expf(val - stats[row * 4]) * stats[row * 4 + 1];
    }
    __syncthreads();
    const float* cbase = cKV + ((size_t)b * TT + t0) * 512 + vh * 128 + vg * 4;
    for (int t = 0; t < sub; t += 2) {
      f32x4 c0 = *(const f32x4*)(cbase + (size_t)t * 512);
      f32x4 c1 = *(const f32x4*)(cbase + (size_t)(t + 1) * 512);
#pragma unroll
      for (int a = 0; a < 4; ++a) {
        float p0 = p_lds[(ng * 4 + a) * 129 + t];
        float p1 = p_lds[(ng * 4 + a) * 129 + t + 1];
#pragma unroll
        for (int j = 0; j < 4; ++j) acc[a][j] += p0 * c0[j] + p1 * c1[j];
      }
    }
  }
#pragma unroll
  for (int a = 0; a < 4; ++a) {
    int n = ng * 4 + a;
    float* dst = aggP + (((size_t)b * NC + chunk) * 32 + n) * 512 + vh * 128 + vg * 4;
    f32x4 v;
#pragma unroll
    for (int j = 0; j < 4; ++j) v[j] = acc[a][j];
    *(f32x4*)dst = v;
  }
}

// ---------------- reduce partials + new-token term -> agg -------------------------
__global__ __launch_bounds__(256) void agg_reduce(const float* __restrict__ aggP,
                                                  const float* __restrict__ stats,
                                                  const float* __restrict__ cKV_t,
                                                  float* __restrict__ agg, int NC) {
  const int idx = blockIdx.x * 256 + threadIdx.x;  // 65536
  const int b = idx >> 14;
  const int n = (idx >> 9) & 31;
  const int v = idx & 511;
  float s = stats[((size_t)(b * 32) + n) * 4 + 2] * cKV_t[b * 512 + v];
  const float* pp = aggP + (((size_t)b * NC) * 32 + n) * 512 + v;
#pragma unroll 4
  for (int c = 0; c < NC; ++c) s += pp[(size_t)c * 32 * 512];
  agg[idx] = s;
}

// ---------------- out1: attn_out[b][n][d] += sum_v agg[b][n][v] * W_UV[v][n][d] ---
__global__ __launch_bounds__(256) void out1_kernel(const float* __restrict__ agg,
                                                   const float* __restrict__ W_UV,
                                                   float* __restrict__ attn_out) {
  const int n = blockIdx.x, vc = blockIdx.y;
  const int tid = threadIdx.x;
  const int d = tid & 127, bh = tid >> 7;
  const float* a0 = agg + ((size_t)(bh * 32) + n) * 512;
  const float* a1 = agg + ((size_t)((bh + 2) * 32) + n) * 512;
  float acc0 = 0.f, acc1 = 0.f;
#pragma unroll 4
  for (int vv = 0; vv < 64; ++vv) {
    int v = vc * 64 + vv;
    float w = W_UV[(size_t)v * 4096 + n * 128 + d];
    acc0 += a0[v] * w;
    acc1 += a1[v] * w;
  }
  atomicAdd(&attn_out[(size_t)bh * 4096 + n * 128 + d], acc0);
  atomicAdd(&attn_out[(size_t)(bh + 2) * 4096 + n * 128 + d], acc1);
}

// ---------------- finalize: f32 output + cache tails ------------------------------
__global__ __launch_bounds__(256) void finalize_kernel(const float* __restrict__ outf,
                                                       const float* __restrict__ cKV_t,
                                                       const float* __restrict__ kR_t,
                                                       float* __restrict__ out) {
  int idx = blockIdx.x * 256 + threadIdx.x;  // 26624 total
  if (idx < 16384) {
    out[idx] = outf[idx];
    return;
  }
  idx -= 16384;
  if (idx < 2048) {
    int b = idx >> 9, v = idx & 511;
    out[16384 + ((size_t)b * T1 + TT) * 512 + v] = cKV_t[idx];
    return;
  }
  idx -= 2048;
  if (idx < 8192) {
    int b = idx >> 11;
    int c = idx & 2047;
    out[16384 + (size_t)8390656 + ((size_t)b * T1 + TT) * 2048 + c] = kR_t[idx];
  }
}

// ---------------- launcher --------------------------------------------------------
extern "C" void kernel_launch(void* const* d_in, const int* in_sizes, int n_in,
                              void* d_out, int out_size, void* d_ws, size_t ws_size,
                              hipStream_t stream) {
  (void)in_sizes; (void)n_in; (void)out_size;
  const float* hidden = (const float*)d_in[0];
  const float* mask   = (const float*)d_in[1];
  const float* cKV    = (const float*)d_in[2];
  const float* kR     = (const float*)d_in[3];
  const float* W_DQ   = (const float*)d_in[4];
  const float* W_DKV  = (const float*)d_in[5];
  const float* W_UQ_C = (const float*)d_in[6];
  const float* W_UQ_R = (const float*)d_in[7];
  const float* W_UK_C = (const float*)d_in[8];
  const float* W_UV_C = (const float*)d_in[9];
  const float* W_KR   = (const float*)d_in[10];
  const float* W_O    = (const float*)d_in[11];

  float* ws = (float*)d_ws;
  // ws layout (float offsets)
  const size_t WS_CQ = 0;           // 6144
  const size_t WS_CKVT = 6144;      // 2048
  const size_t WS_KRT = 8192;       // 8192
  const size_t WS_QC = 16384;       // 16384
  const size_t WS_QR = 32768;       // 8192
  const size_t WS_OUTF = 40960;     // 16384 (atomic target)
  const size_t WS_ATTN = 57344;     // 16384 (atomic target) — zero region [0,73728)
  const size_t WS_STATS = 73728;    // 512 (128 rows x 4: M, 1/S, pTT/S)
  const size_t WS_AGG = 74240;      // 65536
  const size_t WS_QABS = 139776;    // 65536
  const size_t WS_QT = 205312;      // 65536
  const size_t WS_SCORES = 270848;  // 524416
  const size_t WS_SCR = 795264;     // 524416
  const size_t WS_AGGP = 1319680;   // NC*65536 floats of partials

  int NC = 8;
  if (ws_size >= (WS_AGGP + (size_t)64 * 65536) * 4) NC = 64;
  else if (ws_size >= (WS_AGGP + (size_t)32 * 65536) * 4) NC = 32;
  else if (ws_size >= (WS_AGGP + (size_t)16 * 65536) * 4) NC = 16;
  const int tlen = 4096 / NC;

  float* out0 = (float*)d_out;
  float* out_ckv = out0 + 16384;
  float* out_kr = out_ckv + (size_t)8390656;

  hipMemsetAsync(d_ws, 0, 73728 * sizeof(float), stream);

  // projections from hidden (3-in-1)
  gemv_hidden<<<dim3(64, 8, 3), 256, 0, stream>>>(hidden, W_DQ, W_DKV, W_KR, ws);
  // q projections from cQ (2-in-1)
  gemv_cq<<<dim3(128, 4, 2), 256, 0, stream>>>(ws + WS_CQ, W_UQ_C, W_UQ_R,
                                               ws + WS_QC, ws + WS_QR);
  // absorb W_UK into q (both layouts)
  absorb_kernel<<<dim3(32, 4), 128, 0, stream>>>(ws + WS_QC, W_UK_C, ws + WS_QABS, ws + WS_QT);
  // scores + cache copies (block-specialized, global_load_lds + nt stores)
  scores_split<<<6144, 256, 0, stream>>>(cKV, kR, ws + WS_QT, ws + WS_QR,
                                         ws + WS_SCORES, ws + WS_SCR, out_ckv, out_kr);
  // softmax stats (single online pass)
  softmax_stats<<<128, 256, 0, stream>>>(ws + WS_SCORES, ws + WS_SCR, mask, ws + WS_QABS,
                                         ws + WS_CKVT, ws + WS_QR, ws + WS_KRT, ws + WS_STATS);
  // p @ cKV aggregation: partials (probs on the fly) then reduce (+ new-token term)
  agg_part<<<dim3(NC, 4, 4), 256, 0, stream>>>(cKV, ws + WS_SCORES, ws + WS_SCR, mask,
                                               ws + WS_STATS, ws + WS_AGGP, tlen, NC);
  agg_reduce<<<256, 256, 0, stream>>>(ws + WS_AGGP, ws + WS_STATS, ws + WS_CKVT,
                                      ws + WS_AGG, NC);
  // apply W_UV then W_O
  out1_kernel<<<dim3(32, 8), 256, 0, stream>>>(ws + WS_AGG, W_UV_C, ws + WS_ATTN);
  gemv_atomic<<<dim3(128, 8), 256, 0, stream>>>(ws + WS_ATTN, W_O, ws + WS_OUTF, 4096, 4096, 512);
  // f32 output + cache tails
  finalize_kernel<<<104, 256, 0, stream>>>(ws + WS_OUTF, ws + WS_CKVT, ws + WS_KRT, out0);
}

// Round 19
// 194.170 us; speedup vs baseline: 1.0325x; 1.0325x over previous
//
#include <hip/hip_runtime.h>

#define TT 4096
#define T1 4097

using f32x4 = __attribute__((ext_vector_type(4))) float;

// ---------------- shared GEMV body: Y[b][j] += sum_k X[b][k] * W[k][j] ------------
__device__ __forceinline__ void gemv_body(const float* __restrict__ X,
                                          const float* __restrict__ W,
                                          float* __restrict__ Y,
                                          int N, int K, int chunk, int ky) {
  const int tid = threadIdx.x;
  const int ct = tid & 7;
  const int kt = tid >> 3;
  const int col0 = blockIdx.x * 32 + ct * 4;
  const int k0 = ky * chunk;
  float acc[4][4];
#pragma unroll
  for (int c = 0; c < 4; ++c)
#pragma unroll
    for (int b = 0; b < 4; ++b) acc[c][b] = 0.f;
  const int iters = chunk >> 5;
  for (int i = 0; i < iters; ++i) {
    int k = k0 + kt + (i << 5);
    f32x4 w4 = *(const f32x4*)(W + (size_t)k * N + col0);
    float xb[4];
#pragma unroll
    for (int b = 0; b < 4; ++b) xb[b] = X[(size_t)b * K + k];
#pragma unroll
    for (int c = 0; c < 4; ++c)
#pragma unroll
      for (int b = 0; b < 4; ++b) acc[c][b] += w4[c] * xb[b];
  }
  __shared__ float red[256][16];
#pragma unroll
  for (int c = 0; c < 4; ++c)
#pragma unroll
    for (int b = 0; b < 4; ++b) red[tid][c * 4 + b] = acc[c][b];
  __syncthreads();
  for (int s = 16; s >= 1; s >>= 1) {
    if (kt < s) {
#pragma unroll
      for (int j = 0; j < 16; ++j) red[tid][j] += red[tid + 8 * s][j];
    }
    __syncthreads();
  }
  if (kt == 0) {
#pragma unroll
    for (int c = 0; c < 4; ++c)
#pragma unroll
      for (int b = 0; b < 4; ++b)
        atomicAdd(&Y[(size_t)b * N + col0 + c], red[ct][c * 4 + b]);
  }
}

// ---------------- hidden projections: W_DQ / W_DKV / W_KR in one launch -----------
__global__ __launch_bounds__(256) void gemv_hidden(const float* __restrict__ X,
                                                   const float* __restrict__ W0,
                                                   const float* __restrict__ W1,
                                                   const float* __restrict__ W2,
                                                   float* __restrict__ Ybase) {
  const int z = blockIdx.z;
  const float* W = (z == 0) ? W0 : (z == 1) ? W1 : W2;
  const int N = (z == 0) ? 1536 : (z == 1) ? 512 : 2048;
  const int nb = (z == 0) ? 48 : (z == 1) ? 16 : 64;
  const size_t yoff = (z == 0) ? 0 : (z == 1) ? 6144 : 8192;
  if ((int)blockIdx.x >= nb) return;
  gemv_body(X, W, Ybase + yoff, N, 4096, 512, blockIdx.y);
}

// ---------------- cQ projections: W_UQ_C / W_UQ_R in one launch -------------------
__global__ __launch_bounds__(256) void gemv_cq(const float* __restrict__ X,
                                               const float* __restrict__ W0,
                                               const float* __restrict__ W1,
                                               float* __restrict__ Y0,
                                               float* __restrict__ Y1) {
  const int z = blockIdx.z;
  const float* W = (z == 0) ? W0 : W1;
  float* Y = (z == 0) ? Y0 : Y1;
  const int N = (z == 0) ? 4096 : 2048;
  const int nb = (z == 0) ? 128 : 64;
  if ((int)blockIdx.x >= nb) return;
  gemv_body(X, W, Y, N, 1536, 384, blockIdx.y);
}

// ---------------- gemv for W_O ----------------------------------------------------
__global__ __launch_bounds__(256) void gemv_atomic(const float* __restrict__ X,
                                                   const float* __restrict__ W,
                                                   float* __restrict__ Y,
                                                   int N, int K, int chunk) {
  gemv_body(X, W, Y, N, K, chunk, blockIdx.y);
}

// ---------------- absorb: q_abs[b][n][v] + qT[b][v][n] ----------------------------
// grid (32 n, 4 vt); block 128: one thread per v
__global__ __launch_bounds__(128) void absorb_kernel(const float* __restrict__ qC,
                                                     const float* __restrict__ W_UK,
                                                     float* __restrict__ q_abs,
                                                     float* __restrict__ qT) {
  const int n = blockIdx.x, vt = blockIdx.y;
  __shared__ float qs[4][128];
  for (int i = threadIdx.x; i < 512; i += 128)
    qs[i >> 7][i & 127] = qC[(size_t)(i >> 7) * 4096 + n * 128 + (i & 127)];
  __syncthreads();
  const int v = vt * 128 + threadIdx.x;
  const float* wp = W_UK + (size_t)v * 4096 + n * 128;
  float acc[4] = {0.f, 0.f, 0.f, 0.f};
#pragma unroll 8
  for (int c = 0; c < 32; ++c) {
    f32x4 w4 = *(const f32x4*)(wp + c * 4);
#pragma unroll
    for (int j = 0; j < 4; ++j)
#pragma unroll
      for (int b = 0; b < 4; ++b) acc[b] += qs[b][c * 4 + j] * w4[j];
  }
#pragma unroll
  for (int b = 0; b < 4; ++b) {
    q_abs[((size_t)(b * 32) + n) * 512 + v] = acc[b];
    qT[((size_t)b * 512 + v) * 32 + n] = acc[b];
  }
}

// ---------------- new-token masked scaled score per row ---------------------------
// grid 128 (b*32+n); block 64
__global__ __launch_bounds__(64) void newtok_kernel(const float* __restrict__ q_abs,
                                                    const float* __restrict__ cKV_t,
                                                    const float* __restrict__ qR,
                                                    const float* __restrict__ kR_t,
                                                    const float* __restrict__ mask,
                                                    float* __restrict__ valT) {
  const int row = blockIdx.x;
  const int b = row >> 5, n = row & 31;
  const int l = threadIdx.x;
  const float* qa = q_abs + (size_t)row * 512;
  const float* ck = cKV_t + b * 512;
  float p = 0.f;
#pragma unroll
  for (int j = 0; j < 8; ++j) p += qa[l + 64 * j] * ck[l + 64 * j];
  p += qR[(size_t)b * 2048 + n * 64 + l] * kR_t[(size_t)b * 2048 + n * 64 + l];
#pragma unroll
  for (int s = 1; s < 64; s <<= 1) p += __shfl_xor(p, s);
  if (l == 0)
    valT[row] = p * 0.0721687836487032f + mask[(size_t)row * T1 + TT] * (-1e9f);
}

// ---------------- scores + cache copies, block-specialized (R17-verified) ---------
// grid 4096: bid&1==0 -> kR block (8 rows, nt stores), bid&1==1 -> cKV block
__global__ __launch_bounds__(256, 4) void scores_split(const float* __restrict__ cKV,
                                                       const float* __restrict__ kR,
                                                       const float* __restrict__ qT,
                                                       const float* __restrict__ qR,
                                                       float* __restrict__ scores,
                                                       float* __restrict__ scoresR,
                                                       float* __restrict__ out_ckv,
                                                       float* __restrict__ out_kr) {
  const int bid = blockIdx.x;
  const int idx = bid >> 1;
  const int tid = threadIdx.x;
  const int b = idx >> 9;
  const int t0 = (idx & 511) * 8;
  __shared__ float ck[8][516];  // 16.5 KB (ckv branch only)
  if (bid & 1) {
    for (int i = tid; i < 1024; i += 256) {
      int tl = i >> 7, vq = i & 127;
      f32x4 v = *(const f32x4*)(cKV + ((size_t)b * TT + t0 + tl) * 512 + vq * 4);
      *(f32x4*)&ck[tl][vq * 4] = v;
      __builtin_nontemporal_store(v, (f32x4*)(out_ckv + ((size_t)b * T1 + t0 + tl) * 512 + vq * 4));
    }
    __syncthreads();
    const int tl = tid >> 5, n = tid & 31;
    const float* qtb = qT + (size_t)b * 16384 + n;
    float a = 0.f;
#pragma unroll 8
    for (int v = 0; v < 512; ++v) a += qtb[(size_t)v * 32] * ck[tl][v];
    scores[((size_t)(b * 32) + n) * T1 + t0 + tl] = a;
  } else {
    const int w = tid >> 6, l = tid & 63;
    f32x4 q[8];
#pragma unroll
    for (int k = 0; k < 8; ++k)
      q[k] = *(const f32x4*)(qR + (size_t)b * 2048 + l * 4 + k * 256);
    const int nbase = l >> 4;      // head = k*4 + nbase
    const int wlead = ((l & 15) == 0);
#pragma unroll
    for (int r = 0; r < 2; ++r) {
      const int t = t0 + w * 2 + r;
      const float* src = kR + ((size_t)b * TT + t) * 2048 + l * 4;
      float* dst = out_kr + ((size_t)b * T1 + t) * 2048 + l * 4;
      f32x4 v[8];
#pragma unroll
      for (int k = 0; k < 8; ++k) v[k] = *(const f32x4*)(src + k * 256);
#pragma unroll
      for (int k = 0; k < 8; ++k)
        __builtin_nontemporal_store(v[k], (f32x4*)(dst + k * 256));
      float p[8];
#pragma unroll
      for (int k = 0; k < 8; ++k)
        p[k] = (q[k][0] * v[k][0] + q[k][1] * v[k][1]) +
               (q[k][2] * v[k][2] + q[k][3] * v[k][3]);
#pragma unroll
      for (int k = 0; k < 8; ++k) {
        p[k] += __shfl_xor(p[k], 1);
        p[k] += __shfl_xor(p[k], 2);
        p[k] += __shfl_xor(p[k], 4);
        p[k] += __shfl_xor(p[k], 8);
      }
      if (wlead) {
#pragma unroll
        for (int k = 0; k < 8; ++k)
          scoresR[((size_t)(b * 32) + k * 4 + nbase) * T1 + t] = p[k];
      }
    }
  }
}

// ---------------- flash aggregation: chunk-local softmax + partials ---------------
// grid (NC, 4 b, 4 vh of 128 v); block 256: vg = tid&31 (4 v), ng = tid>>5 (4 n)
// Writes unnormalized partials aggP (relative to chunk max) + statsC {m_c, s_c}.
__global__ __launch_bounds__(256) void agg_part(const float* __restrict__ cKV,
                                                const float* __restrict__ scores,
                                                const float* __restrict__ scoresR,
                                                const float* __restrict__ mask,
                                                float* __restrict__ aggP,
                                                float* __restrict__ statsC,
                                                int tlen, int NC) {
  const int chunk = blockIdx.x, b = blockIdx.y, vh = blockIdx.z;
  const int tid = threadIdx.x;
  const int vg = tid & 31, ng = tid >> 5;
  const float isc = 0.0721687836487032f;
  __shared__ float p_lds[32 * 129];
  __shared__ float gm[32], gs[32], scl[32];
  if (tid < 32) { gm[tid] = -1e30f; gs[tid] = 0.f; }
  float acc[4][4];
#pragma unroll
  for (int a = 0; a < 4; ++a)
#pragma unroll
    for (int j = 0; j < 4; ++j) acc[a][j] = 0.f;
  const int sub = (tlen < 128) ? tlen : 128;
  const int sshift = (sub == 64) ? 6 : 7;
  for (int tt = 0; tt < tlen; tt += sub) {
    const int t0 = chunk * tlen + tt;
    __syncthreads();
    // stage raw masked scaled vals
    for (int i = tid; i < (sub << 5); i += 256) {
      int nn = i >> sshift, tl = i & (sub - 1);
      size_t row = (size_t)(b * 32) + nn;
      size_t off = row * T1 + t0 + tl;
      p_lds[nn * 129 + tl] = (scores[off] + scoresR[off]) * isc + mask[off] * (-1e9f);
    }
    __syncthreads();
    // per-n sub max; merge into running gm, compute rescale scl, rescale gs
    {
      const int n8 = tid >> 3, lane = tid & 7;
      float mx = -1e30f;
      for (int t = lane; t < sub; t += 8) mx = fmaxf(mx, p_lds[n8 * 129 + t]);
      mx = fmaxf(mx, __shfl_xor(mx, 1));
      mx = fmaxf(mx, __shfl_xor(mx, 2));
      mx = fmaxf(mx, __shfl_xor(mx, 4));
      if (lane == 0) {
        float newM = fmaxf(gm[n8], mx);
        float sc = __expf(gm[n8] - newM);
        scl[n8] = sc;
        gm[n8] = newM;
        gs[n8] *= sc;
      }
    }
    __syncthreads();
    // rescale acc, exponentiate in place
#pragma unroll
    for (int a = 0; a < 4; ++a) {
      float sc = scl[ng * 4 + a];
#pragma unroll
      for (int j = 0; j < 4; ++j) acc[a][j] *= sc;
    }
    for (int i = tid; i < (sub << 5); i += 256) {
      int nn = i >> sshift, tl = i & (sub - 1);
      p_lds[nn * 129 + tl] = __expf(p_lds[nn * 129 + tl] - gm[nn]);
    }
    __syncthreads();
    // accumulate s per n
    {
      const int n8 = tid >> 3, lane = tid & 7;
      float se = 0.f;
      for (int t = lane; t < sub; t += 8) se += p_lds[n8 * 129 + t];
      se += __shfl_xor(se, 1);
      se += __shfl_xor(se, 2);
      se += __shfl_xor(se, 4);
      if (lane == 0) gs[n8] += se;
    }
    // weighted cKV accumulation
    const float* cbase = cKV + ((size_t)b * TT + t0) * 512 + vh * 128 + vg * 4;
    for (int t = 0; t < sub; t += 2) {
      f32x4 c0 = *(const f32x4*)(cbase + (size_t)t * 512);
      f32x4 c1 = *(const f32x4*)(cbase + (size_t)(t + 1) * 512);
#pragma unroll
      for (int a = 0; a < 4; ++a) {
        float p0 = p_lds[(ng * 4 + a) * 129 + t];
        float p1 = p_lds[(ng * 4 + a) * 129 + t + 1];
#pragma unroll
        for (int j = 0; j < 4; ++j) acc[a][j] += p0 * c0[j] + p1 * c1[j];
      }
    }
  }
  __syncthreads();
#pragma unroll
  for (int a = 0; a < 4; ++a) {
    int n = ng * 4 + a;
    float* dst = aggP + (((size_t)b * NC + chunk) * 32 + n) * 512 + vh * 128 + vg * 4;
    f32x4 v;
#pragma unroll
    for (int j = 0; j < 4; ++j) v[j] = acc[a][j];
    *(f32x4*)dst = v;
  }
  if (vh == 0 && tid < 32) {
    size_t o = ((size_t)(b * 32) + tid) * NC + chunk;
    statsC[2 * o] = gm[tid];
    statsC[2 * o + 1] = gs[tid];
  }
}

// ---------------- merge chunk stats -> per-chunk normalized factors ---------------
// grid 128 (rows); block 64 (c = lane, NC <= 64)
__global__ __launch_bounds__(64) void stats_merge(const float* __restrict__ statsC,
                                                  const float* __restrict__ valT,
                                                  float* __restrict__ fact,
                                                  float* __restrict__ fT, int NC) {
  const int row = blockIdx.x;
  const int l = threadIdx.x;
  const float vt = valT[row];
  float mc = -1e30f, sc = 0.f;
  if (l < NC) {
    mc = statsC[2 * ((size_t)row * NC + l)];
    sc = statsC[2 * ((size_t)row * NC + l) + 1];
  }
  float m = fmaxf(mc, vt);
#pragma unroll
  for (int s = 1; s < 64; s <<= 1) m = fmaxf(m, __shfl_xor(m, s));
  float e = (l < NC) ? sc * __expf(mc - m) : 0.f;
  float S = e;
#pragma unroll
  for (int s = 1; s < 64; s <<= 1) S += __shfl_xor(S, s);
  S += __expf(vt - m);
  const float invS = 1.0f / S;
  if (l < NC) fact[(size_t)row * NC + l] = __expf(mc - m) * invS;
  if (l == 0) fT[row] = __expf(vt - m) * invS;
}

// ---------------- reduce partials with factors + new-token term -> agg ------------
__global__ __launch_bounds__(256) void agg_reduce(const float* __restrict__ aggP,
                                                  const float* __restrict__ fact,
                                                  const float* __restrict__ fT,
                                                  const float* __restrict__ cKV_t,
                                                  float* __restrict__ agg, int NC) {
  const int idx = blockIdx.x * 256 + threadIdx.x;  // 65536
  const int b = idx >> 14;
  const int n = (idx >> 9) & 31;
  const int v = idx & 511;
  const size_t row = (size_t)(b * 32) + n;
  float s = fT[row] * cKV_t[b * 512 + v];
  const float* pp = aggP + (((size_t)b * NC) * 32 + n) * 512 + v;
  const float* fc = fact + row * NC;
#pragma unroll 4
  for (int c = 0; c < NC; ++c) s += pp[(size_t)c * 32 * 512] * fc[c];
  agg[idx] = s;
}

// ---------------- out1: attn_out[b][n][d] += sum_v agg[b][n][v] * W_UV[v][n][d] ---
__global__ __launch_bounds__(256) void out1_kernel(const float* __restrict__ agg,
                                                   const float* __restrict__ W_UV,
                                                   float* __restrict__ attn_out) {
  const int n = blockIdx.x, vc = blockIdx.y;
  const int tid = threadIdx.x;
  const int d = tid & 127, bh = tid >> 7;
  const float* a0 = agg + ((size_t)(bh * 32) + n) * 512;
  const float* a1 = agg + ((size_t)((bh + 2) * 32) + n) * 512;
  float acc0 = 0.f, acc1 = 0.f;
#pragma unroll 4
  for (int vv = 0; vv < 64; ++vv) {
    int v = vc * 64 + vv;
    float w = W_UV[(size_t)v * 4096 + n * 128 + d];
    acc0 += a0[v] * w;
    acc1 += a1[v] * w;
  }
  atomicAdd(&attn_out[(size_t)bh * 4096 + n * 128 + d], acc0);
  atomicAdd(&attn_out[(size_t)(bh + 2) * 4096 + n * 128 + d], acc1);
}

// ---------------- finalize: f32 output + cache tails ------------------------------
__global__ __launch_bounds__(256) void finalize_kernel(const float* __restrict__ outf,
                                                       const float* __restrict__ cKV_t,
                                                       const float* __restrict__ kR_t,
                                                       float* __restrict__ out) {
  int idx = blockIdx.x * 256 + threadIdx.x;  // 26624 total
  if (idx < 16384) {
    out[idx] = outf[idx];
    return;
  }
  idx -= 16384;
  if (idx < 2048) {
    int b = idx >> 9, v = idx & 511;
    out[16384 + ((size_t)b * T1 + TT) * 512 + v] = cKV_t[idx];
    return;
  }
  idx -= 2048;
  if (idx < 8192) {
    int b = idx >> 11;
    int c = idx & 2047;
    out[16384 + (size_t)8390656 + ((size_t)b * T1 + TT) * 2048 + c] = kR_t[idx];
  }
}

// ---------------- launcher --------------------------------------------------------
extern "C" void kernel_launch(void* const* d_in, const int* in_sizes, int n_in,
                              void* d_out, int out_size, void* d_ws, size_t ws_size,
                              hipStream_t stream) {
  (void)in_sizes; (void)n_in; (void)out_size;
  const float* hidden = (const float*)d_in[0];
  const float* mask   = (const float*)d_in[1];
  const float* cKV    = (const float*)d_in[2];
  const float* kR     = (const float*)d_in[3];
  const float* W_DQ   = (const float*)d_in[4];
  const float* W_DKV  = (const float*)d_in[5];
  const float* W_UQ_C = (const float*)d_in[6];
  const float* W_UQ_R = (const float*)d_in[7];
  const float* W_UK_C = (const float*)d_in[8];
  const float* W_UV_C = (const float*)d_in[9];
  const float* W_KR   = (const float*)d_in[10];
  const float* W_O    = (const float*)d_in[11];

  float* ws = (float*)d_ws;
  // ws layout (float offsets)
  const size_t WS_CQ = 0;           // 6144
  const size_t WS_CKVT = 6144;      // 2048
  const size_t WS_KRT = 8192;       // 8192
  const size_t WS_QC = 16384;       // 16384
  const size_t WS_QR = 32768;       // 8192
  const size_t WS_OUTF = 40960;     // 16384 (atomic target)
  const size_t WS_ATTN = 57344;     // 16384 (atomic target) — zero region [0,73728)
  const size_t WS_VALT = 73728;     // 128
  const size_t WS_AGG = 74240;      // 65536
  const size_t WS_QABS = 139776;    // 65536
  const size_t WS_QT = 205312;      // 65536
  const size_t WS_SCORES = 270848;  // 524416
  const size_t WS_SCR = 795264;     // 524416
  const size_t WS_STATSC = 1319680; // 2*128*NC (<= 16384)
  const size_t WS_FACT = 1336064;   // 128*NC (<= 8192)
  const size_t WS_FT = 1344256;     // 128
  const size_t WS_AGGP = 1344512;   // NC*65536 floats of partials

  int NC = 8;
  if (ws_size >= (WS_AGGP + (size_t)64 * 65536) * 4) NC = 64;
  else if (ws_size >= (WS_AGGP + (size_t)32 * 65536) * 4) NC = 32;
  else if (ws_size >= (WS_AGGP + (size_t)16 * 65536) * 4) NC = 16;
  const int tlen = 4096 / NC;

  float* out0 = (float*)d_out;
  float* out_ckv = out0 + 16384;
  float* out_kr = out_ckv + (size_t)8390656;

  hipMemsetAsync(d_ws, 0, 73728 * sizeof(float), stream);

  // projections from hidden (3-in-1)
  gemv_hidden<<<dim3(64, 8, 3), 256, 0, stream>>>(hidden, W_DQ, W_DKV, W_KR, ws);
  // q projections from cQ (2-in-1)
  gemv_cq<<<dim3(128, 4, 2), 256, 0, stream>>>(ws + WS_CQ, W_UQ_C, W_UQ_R,
                                               ws + WS_QC, ws + WS_QR);
  // absorb W_UK into q (both layouts)
  absorb_kernel<<<dim3(32, 4), 128, 0, stream>>>(ws + WS_QC, W_UK_C, ws + WS_QABS, ws + WS_QT);
  // new-token masked scaled score per row
  newtok_kernel<<<128, 64, 0, stream>>>(ws + WS_QABS, ws + WS_CKVT, ws + WS_QR,
                                        ws + WS_KRT, mask, ws + WS_VALT);
  // scores + cache copies (block-specialized, nontemporal copy stores)
  scores_split<<<4096, 256, 0, stream>>>(cKV, kR, ws + WS_QT, ws + WS_QR,
                                         ws + WS_SCORES, ws + WS_SCR, out_ckv, out_kr);
  // flash aggregation: chunk-local softmax + partials + chunk stats
  agg_part<<<dim3(NC, 4, 4), 256, 0, stream>>>(cKV, ws + WS_SCORES, ws + WS_SCR, mask,
                                               ws + WS_AGGP, ws + WS_STATSC, tlen, NC);
  // merge chunk stats into normalized per-chunk factors
  stats_merge<<<128, 64, 0, stream>>>(ws + WS_STATSC, ws + WS_VALT, ws + WS_FACT,
                                      ws + WS_FT, NC);
  // combine partials + new-token term
  agg_reduce<<<256, 256, 0, stream>>>(ws + WS_AGGP, ws + WS_FACT, ws + WS_FT,
                                      ws + WS_CKVT, ws + WS_AGG, NC);
  // apply W_UV then W_O
  out1_kernel<<<dim3(32, 8), 256, 0, stream>>>(ws + WS_AGG, W_UV_C, ws + WS_ATTN);
  gemv_atomic<<<dim3(128, 8), 256, 0, stream>>>(ws + WS_ATTN, W_O, ws + WS_OUTF, 4096, 4096, 512);
  // f32 output + cache tails
  finalize_kernel<<<104, 256, 0, stream>>>(ws + WS_OUTF, ws + WS_CKVT, ws + WS_KRT, out0);
}